// Round 10
// baseline (688.524 us; speedup 1.0000x reference)
//
#include <hip/hip_runtime.h>
#include <hip/hip_bf16.h>

typedef __attribute__((ext_vector_type(8))) __bf16 bf16x8;
typedef __attribute__((ext_vector_type(4))) float floatx4;
typedef unsigned short ushort_t;
typedef unsigned int uint_t;

#define N_NODES 100000
#define NNZ_E   3200000
#define N_IDX   50000
#define NB_BKT  196        // buckets of 512 rows: row >> 9
#define PTILE   8192
#define PBLOCKS 391        // ceil(NNZ_E / PTILE)

__device__ __forceinline__ float bf2f(uint_t u16) {
  union { float f; uint_t i; } v; v.i = u16 << 16; return v.f;
}
__device__ __forceinline__ unsigned short f2bf(float f) {
  union { float f; uint_t i; } v; v.f = f;
  uint_t x = v.i;
  return (unsigned short)((x + 0x7FFFu + ((x >> 16) & 1u)) >> 16);
}
__device__ __forceinline__ uint_t pk(float lo, float hi) {
  return ((uint_t)f2bf(hi) << 16) | (uint_t)f2bf(lo);
}

// ---------------- CSR construction (temporally-dense two-level partition) ---------
// R5 lesson: full-width scatter w/ global row cursors = 8x write-allocate amp
// (199MB WRITE vs 25.6MB payload). Two-level bucket path keeps lines filled
// within one block's lifetime. Keep.

__global__ __launch_bounds__(256) void k_bhist(const int* __restrict__ rows,
                                               int* __restrict__ bcnt) {
  __shared__ int h[NB_BKT];
  for (int i = threadIdx.x; i < NB_BKT; i += 256) h[i] = 0;
  __syncthreads();
  int base = blockIdx.x * PTILE;
  for (int i = threadIdx.x; i < PTILE; i += 256) {
    int e = base + i;
    if (e < NNZ_E) atomicAdd(&h[rows[e] >> 9], 1);
  }
  __syncthreads();
  for (int i = threadIdx.x; i < NB_BKT; i += 256)
    if (h[i]) atomicAdd(&bcnt[i], h[i]);
}

__global__ void k_bscan(const int* __restrict__ bcnt, int* __restrict__ bbase,
                        int* __restrict__ bcur) {
  __shared__ int ts[256];
  int t = threadIdx.x;
  int v = (t < NB_BKT) ? bcnt[t] : 0;
  ts[t] = v;
  __syncthreads();
  for (int off = 1; off < 256; off <<= 1) {
    int x = ts[t];
    int a = (t >= off) ? ts[t - off] : 0;
    __syncthreads();
    ts[t] = x + a;
    __syncthreads();
  }
  if (t < NB_BKT) {
    int b = (t == 0) ? 0 : ts[t - 1];
    bbase[t] = b;
    bcur[t] = b;
  }
}

// partition into 196 coarse buckets; packed edge: col | (row&511)<<17, val
__global__ __launch_bounds__(256) void k_part(const int* __restrict__ rows,
                                              const int* __restrict__ cols,
                                              const float* __restrict__ vals,
                                              int* __restrict__ bcur,
                                              int2* __restrict__ tmp) {
  __shared__ int h[NB_BKT];   // hist, then global write cursor per bucket
  for (int i = threadIdx.x; i < NB_BKT; i += 256) h[i] = 0;
  __syncthreads();
  int base = blockIdx.x * PTILE;
  for (int i = threadIdx.x; i < PTILE; i += 256) {
    int e = base + i;
    if (e < NNZ_E) atomicAdd(&h[rows[e] >> 9], 1);
  }
  __syncthreads();
  for (int i = threadIdx.x; i < NB_BKT; i += 256) {
    int c = h[i];
    h[i] = c ? atomicAdd(&bcur[i], c) : 0;
  }
  __syncthreads();
  for (int i = threadIdx.x; i < PTILE; i += 256) {
    int e = base + i;
    if (e < NNZ_E) {
      int rr = rows[e];
      int p = atomicAdd(&h[rr >> 9], 1);
      int2 o;
      o.x = cols[e] | ((rr & 511) << 17);
      o.y = __float_as_int(vals[e]);
      tmp[p] = o;
    }
  }
}

// one block per bucket: 512-row LDS counting sort -> final edges[] + rowptr
__global__ __launch_bounds__(512) void k_sort(const int* __restrict__ bbase,
                                              const int2* __restrict__ tmp,
                                              int2* __restrict__ edges,
                                              int* __restrict__ rowptr) {
  __shared__ int cnt[512];
  __shared__ int ts[512];
  int b = blockIdx.x, t = threadIdx.x;
  int s = bbase[b];
  int epos = (b == NB_BKT - 1) ? NNZ_E : bbase[b + 1];
  cnt[t] = 0;
  __syncthreads();
  for (int i = s + t; i < epos; i += 512)
    atomicAdd(&cnt[(tmp[i].x >> 17) & 511], 1);
  __syncthreads();
  ts[t] = cnt[t];
  __syncthreads();
  for (int off = 1; off < 512; off <<= 1) {
    int x = ts[t];
    int a = (t >= off) ? ts[t - off] : 0;
    __syncthreads();
    ts[t] = x + a;
    __syncthreads();
  }
  int pre = (t == 0) ? 0 : ts[t - 1];
  int grow = b * 512 + t;
  if (grow < N_NODES) rowptr[grow] = s + pre;
  cnt[t] = s + pre;            // becomes per-row write cursor
  __syncthreads();
  for (int i = s + t; i < epos; i += 512) {
    int2 p = tmp[i];
    int rl = (p.x >> 17) & 511;
    int pos = atomicAdd(&cnt[rl], 1);
    int2 o;
    o.x = p.x & 0x1FFFF;
    o.y = p.y;
    edges[pos] = o;
  }
  if (b == 0 && t == 0) rowptr[N_NODES] = NNZ_E;
}

// ---------------- fused prep: fp32->bf16 convert + weight packing ----------------
// blocks [0,12500): cvt; [12500,12884): prepW1; [12884,13140): prepW2

__global__ __launch_bounds__(256) void k_prep(
    const float4* __restrict__ x, const float* __restrict__ W1,
    const float* __restrict__ W2, ushort4* __restrict__ xb,
    ushort_t* __restrict__ W1p, ushort_t* __restrict__ W2p) {
  int b = blockIdx.x;
  if (b < 12500) {
    int i = b * 256 + threadIdx.x;
    float4 v = x[i];
    ushort4 o;
    o.x = f2bf(v.x); o.y = f2bf(v.y); o.z = f2bf(v.z); o.w = f2bf(v.w);
    xb[i] = o;
  } else if (b < 12884) {
    int kp = b - 12500;   // 0..383
    int n  = threadIdx.x; // 0..255
    int ch = kp >> 7;
    int f  = kp & 127;
    float v;
    if (ch == 0)      v = W1[(f*3+0)*256+n] - W1[(f*3+2)*256+n];
    else if (ch == 1) v = W1[(f*3+1)*256+n];
    else              v = 2.0f * W1[(f*3+2)*256+n];
    int kb = kp >> 5, kr = kp & 31;
    int lane = ((kr >> 3) << 4) | (n & 15);
    W1p[(((size_t)kb * 16 + (n >> 4)) * 64 + lane) * 8 + (kr & 7)] = f2bf(v);
  } else {
    int f = b - 12884;    // 0..255
    int c = threadIdx.x;
    if (c < 192) {
      int g = c >> 6, n = c & 63;
      float v;
      if (g == 0)      v = W2[(f*3+0)*64+n] - W2[(f*3+2)*64+n];
      else if (g == 1) v = W2[(f*3+1)*64+n];
      else             v = 2.0f * W2[(f*3+2)*64+n];
      int kb = f >> 5, kr = f & 31;
      int nb = c >> 4;
      int lane = ((kr >> 3) << 4) | (c & 15);
      W2p[(((size_t)kb * 12 + nb) * 64 + lane) * 8 + (kr & 7)] = f2bf(v);
    }
  }
}

// ---------------- SpMM, 128 features (layer 1) ----------------
// R1 form (best measured, 106.5us/dispatch): scalar edge stream
// (readfirstlane'd row -> s_load, SALU gather bases), 16-deep gather unroll.
// Plateau confirmed across 4 shapes (R1/R3/R7/R8): ~3.5 TB/s L2-fill path.
// DIAGNOSTIC THIS ROUND: each application split into 3 row-chunk dispatches
// (~35us each) so the rocprof top-5 cutoff drops below the hidden mid-size
// kernels (gemm1/gemm2/spmm64s/k_sort) — decomposing the ~380us budget gap.

__global__ __launch_bounds__(256) void k_spmm128(
    const int* __restrict__ rowptr, const int2* __restrict__ edges,
    const ushort_t* __restrict__ in, ushort_t* __restrict__ out, int row0) {
  int r = __builtin_amdgcn_readfirstlane(row0 + blockIdx.x * 4 + (threadIdx.x >> 6));
  int f = threadIdx.x & 63;
  int e0 = rowptr[r], e1 = rowptr[r + 1];
  float a0 = 0.f, a1 = 0.f;
  int e = e0;
  for (; e + 16 <= e1; e += 16) {
    int2 E[16];
#pragma unroll
    for (int j = 0; j < 16; ++j) E[j] = edges[e + j];
    uint_t q[16];
#pragma unroll
    for (int j = 0; j < 16; ++j)
      q[j] = *(const uint_t*)(in + (size_t)E[j].x * 128 + 2 * f);
#pragma unroll
    for (int j = 0; j < 16; ++j) {
      float v = __int_as_float(E[j].y);
      a0 = fmaf(v, bf2f(q[j] & 0xFFFFu), a0);
      a1 = fmaf(v, bf2f(q[j] >> 16), a1);
    }
  }
  for (; e + 4 <= e1; e += 4) {
    int2 E[4];
#pragma unroll
    for (int j = 0; j < 4; ++j) E[j] = edges[e + j];
    uint_t q[4];
#pragma unroll
    for (int j = 0; j < 4; ++j)
      q[j] = *(const uint_t*)(in + (size_t)E[j].x * 128 + 2 * f);
#pragma unroll
    for (int j = 0; j < 4; ++j) {
      float v = __int_as_float(E[j].y);
      a0 = fmaf(v, bf2f(q[j] & 0xFFFFu), a0);
      a1 = fmaf(v, bf2f(q[j] >> 16), a1);
    }
  }
  for (; e < e1; ++e) {
    int2 E = edges[e];
    uint_t q = *(const uint_t*)(in + (size_t)E.x * 128 + 2 * f);
    float v = __int_as_float(E.y);
    a0 = fmaf(v, bf2f(q & 0xFFFFu), a0);
    a1 = fmaf(v, bf2f(q >> 16), a1);
  }
  uint_t o = ((uint_t)f2bf(a1) << 16) | (uint_t)f2bf(a0);
  *(uint_t*)(out + (size_t)r * 128 + 2 * f) = o;
}

// ---------------- SpMM, 64 features: u = p1 + L p2 ----------------
// R7 edge-pair form (perf-equivalent to R1 scalar form).

__global__ __launch_bounds__(256) void k_spmm64_add(
    const int* __restrict__ rowptr, const int2* __restrict__ edges,
    const ushort_t* __restrict__ p2, const ushort_t* __restrict__ p1,
    ushort_t* __restrict__ u) {
  int r = __builtin_amdgcn_readfirstlane(blockIdx.x * 4 + (threadIdx.x >> 6));
  int lane = threadIdx.x & 63;
  int half = lane >> 5, l5 = lane & 31;
  int e0 = rowptr[r], e1 = rowptr[r + 1];
  float a0 = 0.f, a1 = 0.f;
  int e = e0;
  for (; e + 16 <= e1; e += 16) {      // 8 pairs
    int2 Ea[8], Eb[8];
#pragma unroll
    for (int j = 0; j < 8; ++j) { Ea[j] = edges[e + 2*j]; Eb[j] = edges[e + 2*j + 1]; }
    uint_t q[8];
#pragma unroll
    for (int j = 0; j < 8; ++j) {
      int c = half ? Eb[j].x : Ea[j].x;
      q[j] = *(const uint_t*)(p2 + (size_t)c * 64 + 2 * l5);
    }
#pragma unroll
    for (int j = 0; j < 8; ++j) {
      float v = __int_as_float(half ? Eb[j].y : Ea[j].y);
      a0 = fmaf(v, bf2f(q[j] & 0xFFFFu), a0);
      a1 = fmaf(v, bf2f(q[j] >> 16), a1);
    }
  }
  for (; e + 2 <= e1; e += 2) {        // 1 pair
    int2 Ea = edges[e], Eb = edges[e + 1];
    int c = half ? Eb.x : Ea.x;
    uint_t q = *(const uint_t*)(p2 + (size_t)c * 64 + 2 * l5);
    float v = __int_as_float(half ? Eb.y : Ea.y);
    a0 = fmaf(v, bf2f(q & 0xFFFFu), a0);
    a1 = fmaf(v, bf2f(q >> 16), a1);
  }
  if (e < e1) {                        // odd leftover: high half contributes 0
    int2 Ea = edges[e];
    uint_t q = *(const uint_t*)(p2 + (size_t)Ea.x * 64 + 2 * l5);
    float v = half ? 0.f : __int_as_float(Ea.y);
    a0 = fmaf(v, bf2f(q & 0xFFFFu), a0);
    a1 = fmaf(v, bf2f(q >> 16), a1);
  }
  a0 += __shfl_xor(a0, 32);
  a1 += __shfl_xor(a1, 32);
  if (half == 0) {
    uint_t pp = *(const uint_t*)(p1 + (size_t)r * 64 + 2 * l5);
    float b0 = a0 + bf2f(pp & 0xFFFFu);
    float b1 = a1 + bf2f(pp >> 16);
    *(uint_t*)(u + (size_t)r * 64 + 2 * l5) = pk(b0, b1);
  }
}

// ---------------- SpMM, 64 features over idx rows: out = p0[idx] + L u ----------------

__global__ __launch_bounds__(256) void k_spmm64_idx(
    const int* __restrict__ rowptr, const int2* __restrict__ edges,
    const ushort_t* __restrict__ u, const float* __restrict__ p0,
    const int* __restrict__ idx, float* __restrict__ out) {
  int o = __builtin_amdgcn_readfirstlane(blockIdx.x * 4 + (threadIdx.x >> 6));
  int lane = threadIdx.x & 63;
  int half = lane >> 5, l5 = lane & 31;
  int r = __builtin_amdgcn_readfirstlane(idx[o]);
  int e0 = rowptr[r], e1 = rowptr[r + 1];
  float a0 = 0.f, a1 = 0.f;
  int e = e0;
  for (; e + 16 <= e1; e += 16) {      // 8 pairs
    int2 Ea[8], Eb[8];
#pragma unroll
    for (int j = 0; j < 8; ++j) { Ea[j] = edges[e + 2*j]; Eb[j] = edges[e + 2*j + 1]; }
    uint_t q[8];
#pragma unroll
    for (int j = 0; j < 8; ++j) {
      int c = half ? Eb[j].x : Ea[j].x;
      q[j] = *(const uint_t*)(u + (size_t)c * 64 + 2 * l5);
    }
#pragma unroll
    for (int j = 0; j < 8; ++j) {
      float v = __int_as_float(half ? Eb[j].y : Ea[j].y);
      a0 = fmaf(v, bf2f(q[j] & 0xFFFFu), a0);
      a1 = fmaf(v, bf2f(q[j] >> 16), a1);
    }
  }
  for (; e + 2 <= e1; e += 2) {
    int2 Ea = edges[e], Eb = edges[e + 1];
    int c = half ? Eb.x : Ea.x;
    uint_t q = *(const uint_t*)(u + (size_t)c * 64 + 2 * l5);
    float v = __int_as_float(half ? Eb.y : Ea.y);
    a0 = fmaf(v, bf2f(q & 0xFFFFu), a0);
    a1 = fmaf(v, bf2f(q >> 16), a1);
  }
  if (e < e1) {
    int2 Ea = edges[e];
    uint_t q = *(const uint_t*)(u + (size_t)Ea.x * 64 + 2 * l5);
    float v = half ? 0.f : __int_as_float(Ea.y);
    a0 = fmaf(v, bf2f(q & 0xFFFFu), a0);
    a1 = fmaf(v, bf2f(q >> 16), a1);
  }
  a0 += __shfl_xor(a0, 32);
  a1 += __shfl_xor(a1, 32);
  if (half == 0) {
    float2 b = *(const float2*)(p0 + (size_t)r * 64 + 2 * l5);
    float2 ww; ww.x = b.x + a0; ww.y = b.y + a1;
    *(float2*)(out + (size_t)o * 64 + 2 * l5) = ww;
  }
}

// ---------------- GEMM1: h = relu([x|T1|U] @ Weff1 + b1), M=100k K=384 N=256 ----------
// Register-blocked 64x64 tile per wave (Mt=4 x Nt=4).

__global__ __launch_bounds__(256) void k_gemm1(
    const ushort_t* __restrict__ A0, const ushort_t* __restrict__ A1,
    const ushort_t* __restrict__ A2, const ushort_t* __restrict__ Bp,
    const float* __restrict__ bias, ushort_t* __restrict__ h) {
  int lane = threadIdx.x & 63;
  int ng = threadIdx.x >> 6;          // 0..3, cols ng*64 .. ng*64+63
  int r0 = blockIdx.x * 64;
  int mrl = lane & 15;
  int ko = (lane >> 4) << 3;
  floatx4 acc[4][4] = {};             // [mi][nt]
#pragma unroll
  for (int kbg = 0; kbg < 12; ++kbg) {
    int c = kbg >> 2, kb = kbg & 3;
    const ushort_t* Asrc = (c == 0 ? A0 : c == 1 ? A1 : A2);
    bf16x8 a[4];
#pragma unroll
    for (int mi = 0; mi < 4; ++mi) {
      int mr = r0 + mi * 16 + mrl;
      if (mr > N_NODES - 1) mr = N_NODES - 1;     // clamp: loads stay in-bounds
      a[mi] = *(const bf16x8*)(Asrc + (size_t)mr * 128 + kb * 32 + ko);
    }
    const ushort_t* Bb = Bp + (((size_t)(kbg * 16 + ng * 4)) * 64 + lane) * 8;
#pragma unroll
    for (int nt = 0; nt < 4; ++nt) {
      bf16x8 b = *(const bf16x8*)(Bb + (size_t)nt * 64 * 8);
#pragma unroll
      for (int mi = 0; mi < 4; ++mi)
        acc[mi][nt] = __builtin_amdgcn_mfma_f32_16x16x32_bf16(a[mi], b, acc[mi][nt], 0, 0, 0);
    }
  }
  int col0 = ng * 64 + (lane & 15);
  int rr0 = (lane >> 4) << 2;
#pragma unroll
  for (int nt = 0; nt < 4; ++nt) {
    int col = col0 + nt * 16;
    float bv = bias[col];
#pragma unroll
    for (int mi = 0; mi < 4; ++mi) {
      int rb = r0 + mi * 16 + rr0;
#pragma unroll
      for (int rg = 0; rg < 4; ++rg) {
        int row = rb + rg;
        if (row < N_NODES) {
          float v = acc[mi][nt][rg] + bv;
          v = v > 0.f ? v : 0.f;
          h[(size_t)row * 256 + col] = f2bf(v);
        }
      }
    }
  }
}

// ---------------- GEMM2: [p0|p1|p2] = h @ Weff2 (+b2 on p0), M=100k K=256 N=192 -------

__global__ __launch_bounds__(256) void k_gemm2(
    const ushort_t* __restrict__ A, const ushort_t* __restrict__ Bp,
    const float* __restrict__ bias, float* __restrict__ p0,
    ushort_t* __restrict__ p1, ushort_t* __restrict__ p2) {
  int wid = (blockIdx.x * 256 + threadIdx.x) >> 6;   // 0..4691
  int lane = threadIdx.x & 63;
  int mt4 = wid / 3, ng = wid - mt4 * 3;
  if (mt4 >= 1563) return;
  int r0 = mt4 * 64;
  int mrl = lane & 15;
  int ko = (lane >> 4) << 3;
  floatx4 acc[4][4] = {};
#pragma unroll
  for (int kb = 0; kb < 8; ++kb) {
    bf16x8 a[4];
#pragma unroll
    for (int mi = 0; mi < 4; ++mi) {
      int mr = r0 + mi * 16 + mrl;
      if (mr > N_NODES - 1) mr = N_NODES - 1;
      a[mi] = *(const bf16x8*)(A + (size_t)mr * 256 + kb * 32 + ko);
    }
    const ushort_t* Bb = Bp + (((size_t)(kb * 12 + ng * 4)) * 64 + lane) * 8;
#pragma unroll
    for (int nt = 0; nt < 4; ++nt) {
      bf16x8 b = *(const bf16x8*)(Bb + (size_t)nt * 64 * 8);
#pragma unroll
      for (int mi = 0; mi < 4; ++mi)
        acc[mi][nt] = __builtin_amdgcn_mfma_f32_16x16x32_bf16(a[mi], b, acc[mi][nt], 0, 0, 0);
    }
  }
  int c16 = lane & 15;
  int rr0 = (lane >> 4) << 2;
  if (ng == 0) {
#pragma unroll
    for (int nt = 0; nt < 4; ++nt) {
      float bv = bias[nt * 16 + c16];
#pragma unroll
      for (int mi = 0; mi < 4; ++mi) {
        int rb = r0 + mi * 16 + rr0;
#pragma unroll
        for (int rg = 0; rg < 4; ++rg) {
          int row = rb + rg;
          if (row < N_NODES)
            p0[(size_t)row * 64 + nt * 16 + c16] = acc[mi][nt][rg] + bv;
        }
      }
    }
  } else {
    ushort_t* dst = (ng == 1) ? p1 : p2;
#pragma unroll
    for (int nt = 0; nt < 4; ++nt)
#pragma unroll
      for (int mi = 0; mi < 4; ++mi) {
        int rb = r0 + mi * 16 + rr0;
#pragma unroll
        for (int rg = 0; rg < 4; ++rg) {
          int row = rb + rg;
          if (row < N_NODES)
            dst[(size_t)row * 64 + nt * 16 + c16] = f2bf(acc[mi][nt][rg]);
        }
      }
  }
}

// ---------------- launch ----------------

extern "C" void kernel_launch(void* const* d_in, const int* in_sizes, int n_in,
                              void* d_out, int out_size, void* d_ws, size_t ws_size,
                              hipStream_t stream) {
  const float* x    = (const float*)d_in[0];
  const float* vals = (const float*)d_in[1];
  const float* W1   = (const float*)d_in[2];
  const float* b1   = (const float*)d_in[3];
  const float* W2   = (const float*)d_in[4];
  const float* b2   = (const float*)d_in[5];
  const int*   rows = (const int*)d_in[6];
  const int*   cols = (const int*)d_in[7];
  const int*   idx  = (const int*)d_in[8];
  float* out = (float*)d_out;

  char* w = (char*)d_ws;
  size_t off = 0;
  auto take = [&](size_t b) -> char* {
    char* p = w + off;
    off += (b + 255) & ~(size_t)255;
    return p;
  };
  int*      bcnt    = (int*)take((size_t)NB_BKT * 4);
  int*      bbase   = (int*)take((size_t)NB_BKT * 4);
  int*      bcur    = (int*)take((size_t)NB_BKT * 4);
  int*      rowptr  = (int*)take((size_t)(N_NODES + 1) * 4);
  int2*     tmp     = (int2*)take((size_t)NNZ_E * 8);
  int2*     edges   = (int2*)take((size_t)NNZ_E * 8);
  ushort_t* xb      = (ushort_t*)take((size_t)N_NODES * 128 * 2);  // later: p0 (fp32 100k x 64)
  ushort_t* T1a     = (ushort_t*)take((size_t)N_NODES * 128 * 2);  // later: p1 | p2
  ushort_t* U1      = (ushort_t*)take((size_t)N_NODES * 128 * 2);  // later: u
  ushort_t* h       = (ushort_t*)take((size_t)N_NODES * 256 * 2);
  ushort_t* W1p     = (ushort_t*)take((size_t)384 * 256 * 2);
  ushort_t* W2p     = (ushort_t*)take((size_t)256 * 192 * 2);

  // overlays (dead after GEMM1 consumes xb/T1a/U1)
  float*    p0 = (float*)xb;                                   // 25.6 MB, exact fit
  ushort_t* p1 = T1a;                                          // 12.8 MB
  ushort_t* p2 = T1a + (size_t)N_NODES * 64;                   // 12.8 MB
  ushort_t* u  = U1;                                           // 12.8 MB

  // CSR build (graph shared by both layers)
  hipMemsetAsync(bcnt, 0, (size_t)NB_BKT * 4, stream);
  k_bhist<<<PBLOCKS, 256, 0, stream>>>(rows, bcnt);
  k_bscan<<<1, 256, 0, stream>>>(bcnt, bbase, bcur);
  k_part<<<PBLOCKS, 256, 0, stream>>>(rows, cols, vals, bcur, tmp);
  k_sort<<<NB_BKT, 512, 0, stream>>>(bbase, tmp, edges, rowptr);

  // prep (cvt + both weight packs fused)
  k_prep<<<13140, 256, 0, stream>>>((const float4*)x, W1, W2, (ushort4*)xb, W1p, W2p);

  // layer 1: T1 = L x ; U = L T1 ; h = relu([x|T1|U] @ Weff1 + b1)
  // each spmm application split into 3 row-chunk dispatches (diagnostic:
  // drops top-5 cutoff to ~35us so mid-size kernels become visible)
  k_spmm128<<<8334, 256, 0, stream>>>(rowptr, edges, xb, T1a, 0);
  k_spmm128<<<8334, 256, 0, stream>>>(rowptr, edges, xb, T1a, 33336);
  k_spmm128<<<8332, 256, 0, stream>>>(rowptr, edges, xb, T1a, 66672);
  k_spmm128<<<8334, 256, 0, stream>>>(rowptr, edges, T1a, U1, 0);
  k_spmm128<<<8334, 256, 0, stream>>>(rowptr, edges, T1a, U1, 33336);
  k_spmm128<<<8332, 256, 0, stream>>>(rowptr, edges, T1a, U1, 66672);
  k_gemm1<<<1563, 256, 0, stream>>>(xb, T1a, U1, W1p, b1, h);

  // layer 2 (L pushed past the GEMM): [p0|p1|p2] = h @ Weff2 ; u = p1 + L p2 ;
  // out = p0[idx] + (L u)[idx]
  k_gemm2<<<1173, 256, 0, stream>>>(h, W2p, b2, p0, p1, p2);
  k_spmm64_add<<<N_NODES / 4, 256, 0, stream>>>(rowptr, edges, p2, p1, u);
  k_spmm64_idx<<<N_IDX / 4, 256, 0, stream>>>(rowptr, edges, u, p0, idx, out);
}

// Round 11
// 666.658 us; speedup vs baseline: 1.0328x; 1.0328x over previous
//
#include <hip/hip_runtime.h>
#include <hip/hip_bf16.h>

typedef __attribute__((ext_vector_type(8))) __bf16 bf16x8;
typedef __attribute__((ext_vector_type(4))) float floatx4;
typedef unsigned short ushort_t;
typedef unsigned int uint_t;

#define N_NODES 100000
#define NNZ_E   3200000
#define N_IDX   50000
#define NB_BKT  196        // buckets of 512 rows: row >> 9
#define PTILE   8192
#define PBLOCKS 391        // ceil(NNZ_E / PTILE)

__device__ __forceinline__ float bf2f(uint_t u16) {
  union { float f; uint_t i; } v; v.i = u16 << 16; return v.f;
}
__device__ __forceinline__ unsigned short f2bf(float f) {
  union { float f; uint_t i; } v; v.f = f;
  uint_t x = v.i;
  return (unsigned short)((x + 0x7FFFu + ((x >> 16) & 1u)) >> 16);
}
__device__ __forceinline__ uint_t pk(float lo, float hi) {
  return ((uint_t)f2bf(hi) << 16) | (uint_t)f2bf(lo);
}

// ---------------- CSR construction (temporally-dense two-level partition) ---------
// R5 lesson: full-width scatter w/ global row cursors = 8x write-allocate amp.
// Two-level bucket path keeps lines filled within one block's lifetime. Keep.

__global__ __launch_bounds__(256) void k_bhist(const int* __restrict__ rows,
                                               int* __restrict__ bcnt) {
  __shared__ int h[NB_BKT];
  for (int i = threadIdx.x; i < NB_BKT; i += 256) h[i] = 0;
  __syncthreads();
  int base = blockIdx.x * PTILE;
  for (int i = threadIdx.x; i < PTILE; i += 256) {
    int e = base + i;
    if (e < NNZ_E) atomicAdd(&h[rows[e] >> 9], 1);
  }
  __syncthreads();
  for (int i = threadIdx.x; i < NB_BKT; i += 256)
    if (h[i]) atomicAdd(&bcnt[i], h[i]);
}

__global__ void k_bscan(const int* __restrict__ bcnt, int* __restrict__ bbase,
                        int* __restrict__ bcur) {
  __shared__ int ts[256];
  int t = threadIdx.x;
  int v = (t < NB_BKT) ? bcnt[t] : 0;
  ts[t] = v;
  __syncthreads();
  for (int off = 1; off < 256; off <<= 1) {
    int x = ts[t];
    int a = (t >= off) ? ts[t - off] : 0;
    __syncthreads();
    ts[t] = x + a;
    __syncthreads();
  }
  if (t < NB_BKT) {
    int b = (t == 0) ? 0 : ts[t - 1];
    bbase[t] = b;
    bcur[t] = b;
  }
}

// partition into 196 coarse buckets; packed edge: col | (row&511)<<17, val
__global__ __launch_bounds__(256) void k_part(const int* __restrict__ rows,
                                              const int* __restrict__ cols,
                                              const float* __restrict__ vals,
                                              int* __restrict__ bcur,
                                              int2* __restrict__ tmp) {
  __shared__ int h[NB_BKT];   // hist, then global write cursor per bucket
  for (int i = threadIdx.x; i < NB_BKT; i += 256) h[i] = 0;
  __syncthreads();
  int base = blockIdx.x * PTILE;
  for (int i = threadIdx.x; i < PTILE; i += 256) {
    int e = base + i;
    if (e < NNZ_E) atomicAdd(&h[rows[e] >> 9], 1);
  }
  __syncthreads();
  for (int i = threadIdx.x; i < NB_BKT; i += 256) {
    int c = h[i];
    h[i] = c ? atomicAdd(&bcur[i], c) : 0;
  }
  __syncthreads();
  for (int i = threadIdx.x; i < PTILE; i += 256) {
    int e = base + i;
    if (e < NNZ_E) {
      int rr = rows[e];
      int p = atomicAdd(&h[rr >> 9], 1);
      int2 o;
      o.x = cols[e] | ((rr & 511) << 17);
      o.y = __float_as_int(vals[e]);
      tmp[p] = o;
    }
  }
}

// one block per bucket: 512-row LDS counting sort -> final edges[] + rowptr
__global__ __launch_bounds__(512) void k_sort(const int* __restrict__ bbase,
                                              const int2* __restrict__ tmp,
                                              int2* __restrict__ edges,
                                              int* __restrict__ rowptr) {
  __shared__ int cnt[512];
  __shared__ int ts[512];
  int b = blockIdx.x, t = threadIdx.x;
  int s = bbase[b];
  int epos = (b == NB_BKT - 1) ? NNZ_E : bbase[b + 1];
  cnt[t] = 0;
  __syncthreads();
  for (int i = s + t; i < epos; i += 512)
    atomicAdd(&cnt[(tmp[i].x >> 17) & 511], 1);
  __syncthreads();
  ts[t] = cnt[t];
  __syncthreads();
  for (int off = 1; off < 512; off <<= 1) {
    int x = ts[t];
    int a = (t >= off) ? ts[t - off] : 0;
    __syncthreads();
    ts[t] = x + a;
    __syncthreads();
  }
  int pre = (t == 0) ? 0 : ts[t - 1];
  int grow = b * 512 + t;
  if (grow < N_NODES) rowptr[grow] = s + pre;
  cnt[t] = s + pre;            // becomes per-row write cursor
  __syncthreads();
  for (int i = s + t; i < epos; i += 512) {
    int2 p = tmp[i];
    int rl = (p.x >> 17) & 511;
    int pos = atomicAdd(&cnt[rl], 1);
    int2 o;
    o.x = p.x & 0x1FFFF;
    o.y = p.y;
    edges[pos] = o;
  }
  if (b == 0 && t == 0) rowptr[N_NODES] = NNZ_E;
}

// ---------------- fused prep: fp32->bf16 convert + weight packing ----------------
// blocks [0,12500): cvt; [12500,12884): prepW1; [12884,13140): prepW2

__global__ __launch_bounds__(256) void k_prep(
    const float4* __restrict__ x, const float* __restrict__ W1,
    const float* __restrict__ W2, ushort4* __restrict__ xb,
    ushort_t* __restrict__ W1p, ushort_t* __restrict__ W2p) {
  int b = blockIdx.x;
  if (b < 12500) {
    int i = b * 256 + threadIdx.x;
    float4 v = x[i];
    ushort4 o;
    o.x = f2bf(v.x); o.y = f2bf(v.y); o.z = f2bf(v.z); o.w = f2bf(v.w);
    xb[i] = o;
  } else if (b < 12884) {
    int kp = b - 12500;   // 0..383
    int n  = threadIdx.x; // 0..255
    int ch = kp >> 7;
    int f  = kp & 127;
    float v;
    if (ch == 0)      v = W1[(f*3+0)*256+n] - W1[(f*3+2)*256+n];
    else if (ch == 1) v = W1[(f*3+1)*256+n];
    else              v = 2.0f * W1[(f*3+2)*256+n];
    int kb = kp >> 5, kr = kp & 31;
    int lane = ((kr >> 3) << 4) | (n & 15);
    W1p[(((size_t)kb * 16 + (n >> 4)) * 64 + lane) * 8 + (kr & 7)] = f2bf(v);
  } else {
    int f = b - 12884;    // 0..255
    int c = threadIdx.x;
    if (c < 192) {
      int g = c >> 6, n = c & 63;
      float v;
      if (g == 0)      v = W2[(f*3+0)*64+n] - W2[(f*3+2)*64+n];
      else if (g == 1) v = W2[(f*3+1)*64+n];
      else             v = 2.0f * W2[(f*3+2)*64+n];
      int kb = f >> 5, kr = f & 31;
      int nb = c >> 4;
      int lane = ((kr >> 3) << 4) | (c & 15);
      W2p[(((size_t)kb * 12 + nb) * 64 + lane) * 8 + (kr & 7)] = f2bf(v);
    }
  }
}

// ---------------- SpMM, 128 features (layer 1) ----------------
// R1 form (best measured, ~106us full / ~36us per third). Plateau confirmed
// across 4 shapes: ~3.5 TB/s L2-fill path. 3-way split kept for profiling
// visibility of the mid-size kernels.

__global__ __launch_bounds__(256) void k_spmm128(
    const int* __restrict__ rowptr, const int2* __restrict__ edges,
    const ushort_t* __restrict__ in, ushort_t* __restrict__ out, int row0) {
  int r = __builtin_amdgcn_readfirstlane(row0 + blockIdx.x * 4 + (threadIdx.x >> 6));
  int f = threadIdx.x & 63;
  int e0 = rowptr[r], e1 = rowptr[r + 1];
  float a0 = 0.f, a1 = 0.f;
  int e = e0;
  for (; e + 16 <= e1; e += 16) {
    int2 E[16];
#pragma unroll
    for (int j = 0; j < 16; ++j) E[j] = edges[e + j];
    uint_t q[16];
#pragma unroll
    for (int j = 0; j < 16; ++j)
      q[j] = *(const uint_t*)(in + (size_t)E[j].x * 128 + 2 * f);
#pragma unroll
    for (int j = 0; j < 16; ++j) {
      float v = __int_as_float(E[j].y);
      a0 = fmaf(v, bf2f(q[j] & 0xFFFFu), a0);
      a1 = fmaf(v, bf2f(q[j] >> 16), a1);
    }
  }
  for (; e + 4 <= e1; e += 4) {
    int2 E[4];
#pragma unroll
    for (int j = 0; j < 4; ++j) E[j] = edges[e + j];
    uint_t q[4];
#pragma unroll
    for (int j = 0; j < 4; ++j)
      q[j] = *(const uint_t*)(in + (size_t)E[j].x * 128 + 2 * f);
#pragma unroll
    for (int j = 0; j < 4; ++j) {
      float v = __int_as_float(E[j].y);
      a0 = fmaf(v, bf2f(q[j] & 0xFFFFu), a0);
      a1 = fmaf(v, bf2f(q[j] >> 16), a1);
    }
  }
  for (; e < e1; ++e) {
    int2 E = edges[e];
    uint_t q = *(const uint_t*)(in + (size_t)E.x * 128 + 2 * f);
    float v = __int_as_float(E.y);
    a0 = fmaf(v, bf2f(q & 0xFFFFu), a0);
    a1 = fmaf(v, bf2f(q >> 16), a1);
  }
  uint_t o = ((uint_t)f2bf(a1) << 16) | (uint_t)f2bf(a0);
  *(uint_t*)(out + (size_t)r * 128 + 2 * f) = o;
}

// ---------------- SpMM, 64 features: u = p1 + L p2 ----------------

__global__ __launch_bounds__(256) void k_spmm64_add(
    const int* __restrict__ rowptr, const int2* __restrict__ edges,
    const ushort_t* __restrict__ p2, const ushort_t* __restrict__ p1,
    ushort_t* __restrict__ u) {
  int r = __builtin_amdgcn_readfirstlane(blockIdx.x * 4 + (threadIdx.x >> 6));
  int lane = threadIdx.x & 63;
  int half = lane >> 5, l5 = lane & 31;
  int e0 = rowptr[r], e1 = rowptr[r + 1];
  float a0 = 0.f, a1 = 0.f;
  int e = e0;
  for (; e + 16 <= e1; e += 16) {      // 8 pairs
    int2 Ea[8], Eb[8];
#pragma unroll
    for (int j = 0; j < 8; ++j) { Ea[j] = edges[e + 2*j]; Eb[j] = edges[e + 2*j + 1]; }
    uint_t q[8];
#pragma unroll
    for (int j = 0; j < 8; ++j) {
      int c = half ? Eb[j].x : Ea[j].x;
      q[j] = *(const uint_t*)(p2 + (size_t)c * 64 + 2 * l5);
    }
#pragma unroll
    for (int j = 0; j < 8; ++j) {
      float v = __int_as_float(half ? Eb[j].y : Ea[j].y);
      a0 = fmaf(v, bf2f(q[j] & 0xFFFFu), a0);
      a1 = fmaf(v, bf2f(q[j] >> 16), a1);
    }
  }
  for (; e + 2 <= e1; e += 2) {        // 1 pair
    int2 Ea = edges[e], Eb = edges[e + 1];
    int c = half ? Eb.x : Ea.x;
    uint_t q = *(const uint_t*)(p2 + (size_t)c * 64 + 2 * l5);
    float v = __int_as_float(half ? Eb.y : Ea.y);
    a0 = fmaf(v, bf2f(q & 0xFFFFu), a0);
    a1 = fmaf(v, bf2f(q >> 16), a1);
  }
  if (e < e1) {                        // odd leftover: high half contributes 0
    int2 Ea = edges[e];
    uint_t q = *(const uint_t*)(p2 + (size_t)Ea.x * 64 + 2 * l5);
    float v = half ? 0.f : __int_as_float(Ea.y);
    a0 = fmaf(v, bf2f(q & 0xFFFFu), a0);
    a1 = fmaf(v, bf2f(q >> 16), a1);
  }
  a0 += __shfl_xor(a0, 32);
  a1 += __shfl_xor(a1, 32);
  if (half == 0) {
    uint_t pp = *(const uint_t*)(p1 + (size_t)r * 64 + 2 * l5);
    float b0 = a0 + bf2f(pp & 0xFFFFu);
    float b1 = a1 + bf2f(pp >> 16);
    *(uint_t*)(u + (size_t)r * 64 + 2 * l5) = pk(b0, b1);
  }
}

// ---------------- SpMM, 64 features over idx rows: out = p0[idx] + L u ----------------

__global__ __launch_bounds__(256) void k_spmm64_idx(
    const int* __restrict__ rowptr, const int2* __restrict__ edges,
    const ushort_t* __restrict__ u, const float* __restrict__ p0,
    const int* __restrict__ idx, float* __restrict__ out) {
  int o = __builtin_amdgcn_readfirstlane(blockIdx.x * 4 + (threadIdx.x >> 6));
  int lane = threadIdx.x & 63;
  int half = lane >> 5, l5 = lane & 31;
  int r = __builtin_amdgcn_readfirstlane(idx[o]);
  int e0 = rowptr[r], e1 = rowptr[r + 1];
  float a0 = 0.f, a1 = 0.f;
  int e = e0;
  for (; e + 16 <= e1; e += 16) {      // 8 pairs
    int2 Ea[8], Eb[8];
#pragma unroll
    for (int j = 0; j < 8; ++j) { Ea[j] = edges[e + 2*j]; Eb[j] = edges[e + 2*j + 1]; }
    uint_t q[8];
#pragma unroll
    for (int j = 0; j < 8; ++j) {
      int c = half ? Eb[j].x : Ea[j].x;
      q[j] = *(const uint_t*)(u + (size_t)c * 64 + 2 * l5);
    }
#pragma unroll
    for (int j = 0; j < 8; ++j) {
      float v = __int_as_float(half ? Eb[j].y : Ea[j].y);
      a0 = fmaf(v, bf2f(q[j] & 0xFFFFu), a0);
      a1 = fmaf(v, bf2f(q[j] >> 16), a1);
    }
  }
  for (; e + 2 <= e1; e += 2) {
    int2 Ea = edges[e], Eb = edges[e + 1];
    int c = half ? Eb.x : Ea.x;
    uint_t q = *(const uint_t*)(u + (size_t)c * 64 + 2 * l5);
    float v = __int_as_float(half ? Eb.y : Ea.y);
    a0 = fmaf(v, bf2f(q & 0xFFFFu), a0);
    a1 = fmaf(v, bf2f(q >> 16), a1);
  }
  if (e < e1) {
    int2 Ea = edges[e];
    uint_t q = *(const uint_t*)(u + (size_t)Ea.x * 64 + 2 * l5);
    float v = half ? 0.f : __int_as_float(Ea.y);
    a0 = fmaf(v, bf2f(q & 0xFFFFu), a0);
    a1 = fmaf(v, bf2f(q >> 16), a1);
  }
  a0 += __shfl_xor(a0, 32);
  a1 += __shfl_xor(a1, 32);
  if (half == 0) {
    float2 b = *(const float2*)(p0 + (size_t)r * 64 + 2 * l5);
    float2 ww; ww.x = b.x + a0; ww.y = b.y + a1;
    *(float2*)(out + (size_t)o * 64 + 2 * l5) = ww;
  }
}

// ---------------- GEMM1: h = relu([x|T1|U] @ Weff1 + b1), M=100k K=384 N=256 ----------
// R10 profile: 90us at MfmaUtil 8% — latency-serialized per-wave loads.
// Rewritten in the canonical LDS-staged 2-barrier structure (m97): 128x128
// tile, BK=64, 6 K-steps. A staged row-major with k-chunk XOR swizzle
// (pre-swizzled GLOBAL source + swizzled ds_read — linear LDS dest as
// global_load_lds requires); B's fragment-pack is already contiguous 1KB
// chunks -> conflict-free lane*16B reads, no swizzle needed.

__global__ __launch_bounds__(256) void k_gemm1(
    const ushort_t* __restrict__ A0, const ushort_t* __restrict__ A1,
    const ushort_t* __restrict__ A2, const ushort_t* __restrict__ Bp,
    const float* __restrict__ bias, ushort_t* __restrict__ h) {
  __shared__ ushort_t sA[128 * 64];   // 16 KB, [row][k8-slot], slot = k8 ^ (row&7)
  __shared__ ushort_t sB[16 * 512];   // 16 KB, 16 chunks of (kb_l, nb_l)
  int t = threadIdx.x, w = t >> 6, l = t & 63;
  int mt = blockIdx.x >> 1, ct = blockIdx.x & 1;
  int r0 = mt * 128;
  int wr = w >> 1, wc = w & 1;
  floatx4 acc[4][4] = {};
  for (int s = 0; s < 6; ++s) {
    const ushort_t* Asrc = (s < 2) ? A0 : (s < 4) ? A1 : A2;
    int kloc = (s & 1) << 6;
#pragma unroll
    for (int c = 0; c < 4; ++c) {     // A: 128 rows x 64 k = 16KB, 4 calls
      int rl = c * 32 + (t >> 3);
      int row = r0 + rl; if (row > N_NODES - 1) row = N_NODES - 1;
      int k8f = (t & 7) ^ (rl & 7);   // pre-swizzled global source
      __builtin_amdgcn_global_load_lds(
          (const void*)(Asrc + (size_t)row * 128 + kloc + k8f * 8),
          (void*)(sA + (c * 4 + w) * 512), 16, 0, 0);
    }
#pragma unroll
    for (int i = 0; i < 4; ++i) {     // B: 16 chunks x 1KB, 4 calls
      int lc = i * 4 + w;
      int chunkid = (s * 2 + (lc >> 3)) * 16 + ct * 8 + (lc & 7);
      __builtin_amdgcn_global_load_lds(
          (const void*)(Bp + (size_t)chunkid * 512 + l * 8),
          (void*)(sB + lc * 512), 16, 0, 0);
    }
    __syncthreads();
#pragma unroll
    for (int kb = 0; kb < 2; ++kb) {
      bf16x8 aF[4], bF[4];
      int k8 = kb * 4 + (l >> 4);
#pragma unroll
      for (int mi = 0; mi < 4; ++mi) {
        int rl = wr * 64 + mi * 16 + (l & 15);
        aF[mi] = *(const bf16x8*)(sA + rl * 64 + ((k8 ^ (rl & 7)) * 8));
      }
#pragma unroll
      for (int nt = 0; nt < 4; ++nt)
        bF[nt] = *(const bf16x8*)(sB + ((size_t)(kb * 8 + wc * 4 + nt) * 64 + l) * 8);
#pragma unroll
      for (int nt = 0; nt < 4; ++nt)
#pragma unroll
        for (int mi = 0; mi < 4; ++mi)
          acc[mi][nt] = __builtin_amdgcn_mfma_f32_16x16x32_bf16(aF[mi], bF[nt], acc[mi][nt], 0, 0, 0);
    }
    __syncthreads();
  }
  int col0 = ct * 128 + wc * 64 + (l & 15);
  int rb0 = r0 + wr * 64 + ((l >> 4) << 2);
#pragma unroll
  for (int nt = 0; nt < 4; ++nt) {
    int col = col0 + nt * 16;
    float bv = bias[col];
#pragma unroll
    for (int mi = 0; mi < 4; ++mi) {
#pragma unroll
      for (int rg = 0; rg < 4; ++rg) {
        int row = rb0 + mi * 16 + rg;
        if (row < N_NODES) {
          float v = acc[mi][nt][rg] + bv;
          v = v > 0.f ? v : 0.f;
          h[(size_t)row * 256 + col] = f2bf(v);
        }
      }
    }
  }
}

// ---------------- GEMM2: [p0|p1|p2] = h @ Weff2 (+b2 on p0), M=100k K=256 N=192 -------
// Same LDS-staged structure: 256x64 tile (block-uniform output slab ct),
// 4 K-steps. Grid = 391 Mtiles x 3 slabs = 1173.

__global__ __launch_bounds__(256) void k_gemm2(
    const ushort_t* __restrict__ A, const ushort_t* __restrict__ Bp,
    const float* __restrict__ bias, float* __restrict__ p0,
    ushort_t* __restrict__ p1, ushort_t* __restrict__ p2) {
  __shared__ ushort_t sA[256 * 64];   // 32 KB
  __shared__ ushort_t sB[8 * 512];    // 8 KB
  int t = threadIdx.x, w = t >> 6, l = t & 63;
  int mt = blockIdx.x / 3, ct = blockIdx.x - mt * 3;
  int r0 = mt * 256;
  floatx4 acc[4][4] = {};
  for (int s = 0; s < 4; ++s) {
    int kloc = s * 64;
#pragma unroll
    for (int c = 0; c < 8; ++c) {     // A: 256 rows x 64 k = 32KB, 8 calls
      int rl = c * 32 + (t >> 3);
      int row = r0 + rl; if (row > N_NODES - 1) row = N_NODES - 1;
      int k8f = (t & 7) ^ (rl & 7);
      __builtin_amdgcn_global_load_lds(
          (const void*)(A + (size_t)row * 256 + kloc + k8f * 8),
          (void*)(sA + (c * 4 + w) * 512), 16, 0, 0);
    }
#pragma unroll
    for (int i = 0; i < 2; ++i) {     // B: 8 chunks x 1KB, 2 calls
      int lc = i * 4 + w;
      int chunkid = (s * 2 + (lc >> 2)) * 12 + ct * 4 + (lc & 3);
      __builtin_amdgcn_global_load_lds(
          (const void*)(Bp + (size_t)chunkid * 512 + l * 8),
          (void*)(sB + lc * 512), 16, 0, 0);
    }
    __syncthreads();
#pragma unroll
    for (int kb = 0; kb < 2; ++kb) {
      bf16x8 aF[4], bF[4];
      int k8 = kb * 4 + (l >> 4);
#pragma unroll
      for (int mi = 0; mi < 4; ++mi) {
        int rl = w * 64 + mi * 16 + (l & 15);
        aF[mi] = *(const bf16x8*)(sA + rl * 64 + ((k8 ^ (rl & 7)) * 8));
      }
#pragma unroll
      for (int nt = 0; nt < 4; ++nt)
        bF[nt] = *(const bf16x8*)(sB + ((size_t)(kb * 4 + nt) * 64 + l) * 8);
#pragma unroll
      for (int nt = 0; nt < 4; ++nt)
#pragma unroll
        for (int mi = 0; mi < 4; ++mi)
          acc[mi][nt] = __builtin_amdgcn_mfma_f32_16x16x32_bf16(aF[mi], bF[nt], acc[mi][nt], 0, 0, 0);
    }
    __syncthreads();
  }
  int c16 = l & 15;
  int rb0 = r0 + w * 64 + ((l >> 4) << 2);
  if (ct == 0) {
#pragma unroll
    for (int nt = 0; nt < 4; ++nt) {
      float bv = bias[nt * 16 + c16];
#pragma unroll
      for (int mi = 0; mi < 4; ++mi)
#pragma unroll
        for (int rg = 0; rg < 4; ++rg) {
          int row = rb0 + mi * 16 + rg;
          if (row < N_NODES)
            p0[(size_t)row * 64 + nt * 16 + c16] = acc[mi][nt][rg] + bv;
        }
    }
  } else {
    ushort_t* dst = (ct == 1) ? p1 : p2;
#pragma unroll
    for (int nt = 0; nt < 4; ++nt)
#pragma unroll
      for (int mi = 0; mi < 4; ++mi)
#pragma unroll
        for (int rg = 0; rg < 4; ++rg) {
          int row = rb0 + mi * 16 + rg;
          if (row < N_NODES)
            dst[(size_t)row * 64 + nt * 16 + c16] = f2bf(acc[mi][nt][rg]);
        }
  }
}

// ---------------- launch ----------------

extern "C" void kernel_launch(void* const* d_in, const int* in_sizes, int n_in,
                              void* d_out, int out_size, void* d_ws, size_t ws_size,
                              hipStream_t stream) {
  const float* x    = (const float*)d_in[0];
  const float* vals = (const float*)d_in[1];
  const float* W1   = (const float*)d_in[2];
  const float* b1   = (const float*)d_in[3];
  const float* W2   = (const float*)d_in[4];
  const float* b2   = (const float*)d_in[5];
  const int*   rows = (const int*)d_in[6];
  const int*   cols = (const int*)d_in[7];
  const int*   idx  = (const int*)d_in[8];
  float* out = (float*)d_out;

  char* w = (char*)d_ws;
  size_t off = 0;
  auto take = [&](size_t b) -> char* {
    char* p = w + off;
    off += (b + 255) & ~(size_t)255;
    return p;
  };
  int*      bcnt    = (int*)take((size_t)NB_BKT * 4);
  int*      bbase   = (int*)take((size_t)NB_BKT * 4);
  int*      bcur    = (int*)take((size_t)NB_BKT * 4);
  int*      rowptr  = (int*)take((size_t)(N_NODES + 1) * 4);
  int2*     tmp     = (int2*)take((size_t)NNZ_E * 8);
  int2*     edges   = (int2*)take((size_t)NNZ_E * 8);
  ushort_t* xb      = (ushort_t*)take((size_t)N_NODES * 128 * 2);  // later: p0 (fp32 100k x 64)
  ushort_t* T1a     = (ushort_t*)take((size_t)N_NODES * 128 * 2);  // later: p1 | p2
  ushort_t* U1      = (ushort_t*)take((size_t)N_NODES * 128 * 2);  // later: u
  ushort_t* h       = (ushort_t*)take((size_t)N_NODES * 256 * 2);
  ushort_t* W1p     = (ushort_t*)take((size_t)384 * 256 * 2);
  ushort_t* W2p     = (ushort_t*)take((size_t)256 * 192 * 2);

  // overlays (dead after GEMM1 consumes xb/T1a/U1)
  float*    p0 = (float*)xb;                                   // 25.6 MB, exact fit
  ushort_t* p1 = T1a;                                          // 12.8 MB
  ushort_t* p2 = T1a + (size_t)N_NODES * 64;                   // 12.8 MB
  ushort_t* u  = U1;                                           // 12.8 MB

  // CSR build (graph shared by both layers)
  hipMemsetAsync(bcnt, 0, (size_t)NB_BKT * 4, stream);
  k_bhist<<<PBLOCKS, 256, 0, stream>>>(rows, bcnt);
  k_bscan<<<1, 256, 0, stream>>>(bcnt, bbase, bcur);
  k_part<<<PBLOCKS, 256, 0, stream>>>(rows, cols, vals, bcur, tmp);
  k_sort<<<NB_BKT, 512, 0, stream>>>(bbase, tmp, edges, rowptr);

  // prep (cvt + both weight packs fused)
  k_prep<<<13140, 256, 0, stream>>>((const float4*)x, W1, W2, (ushort4*)xb, W1p, W2p);

  // layer 1: T1 = L x ; U = L T1 ; h = relu([x|T1|U] @ Weff1 + b1)
  k_spmm128<<<8334, 256, 0, stream>>>(rowptr, edges, xb, T1a, 0);
  k_spmm128<<<8334, 256, 0, stream>>>(rowptr, edges, xb, T1a, 33336);
  k_spmm128<<<8332, 256, 0, stream>>>(rowptr, edges, xb, T1a, 66672);
  k_spmm128<<<8334, 256, 0, stream>>>(rowptr, edges, T1a, U1, 0);
  k_spmm128<<<8334, 256, 0, stream>>>(rowptr, edges, T1a, U1, 33336);
  k_spmm128<<<8332, 256, 0, stream>>>(rowptr, edges, T1a, U1, 66672);
  k_gemm1<<<1564, 256, 0, stream>>>(xb, T1a, U1, W1p, b1, h);

  // layer 2 (L pushed past the GEMM): [p0|p1|p2] = h @ Weff2 ; u = p1 + L p2 ;
  // out = p0[idx] + (L u)[idx]
  k_gemm2<<<1173, 256, 0, stream>>>(h, W2p, b2, p0, p1, p2);
  k_spmm64_add<<<N_NODES / 4, 256, 0, stream>>>(rowptr, edges, p2, p1, u);
  k_spmm64_idx<<<N_IDX / 4, 256, 0, stream>>>(rowptr, edges, u, p0, idx, out);
}

// Round 12
// 633.959 us; speedup vs baseline: 1.0861x; 1.0516x over previous
//
#include <hip/hip_runtime.h>
#include <hip/hip_bf16.h>

typedef __attribute__((ext_vector_type(8))) __bf16 bf16x8;
typedef __attribute__((ext_vector_type(4))) float floatx4;
typedef unsigned short ushort_t;
typedef unsigned int uint_t;

#define N_NODES 100000
#define NNZ_E   3200000
#define N_IDX   50000
#define NB_BKT  196        // buckets of 512 rows: row >> 9
#define PTILE   8192
#define PBLOCKS 391        // ceil(NNZ_E / PTILE)
#define BCAP    18432      // fixed per-bucket tmp capacity (mean 16384, sd ~127)

__device__ __forceinline__ float bf2f(uint_t u16) {
  union { float f; uint_t i; } v; v.i = u16 << 16; return v.f;
}
__device__ __forceinline__ unsigned short f2bf(float f) {
  union { float f; uint_t i; } v; v.f = f;
  uint_t x = v.i;
  return (unsigned short)((x + 0x7FFFu + ((x >> 16) & 1u)) >> 16);
}
__device__ __forceinline__ uint_t pk(float lo, float hi) {
  return ((uint_t)f2bf(hi) << 16) | (uint_t)f2bf(lo);
}

// ---------------- CSR construction (two-level partition, de-latencied) ----------
// R11 profile: k_part 72us at VALUBusy 2.5% / Occ 13.5% — pure latency
// starvation (4 waves/block, 32 serial LDS-atomic edges/thread). Fixes:
// (1) fixed-capacity tmp (BCAP) lets k_part reserve ranges directly -> k_bhist
//     and its rows[] pass are eliminated;
// (2) k_part/k_sort at 1024 threads (16 waves/block) -> 4x latency hiding.
// R5 lesson stands: bucket-contiguous tmp writes avoid write-allocate amp.

__global__ void k_init(int* __restrict__ bcur) {
  int t = threadIdx.x;
  if (t < NB_BKT) bcur[t] = t * BCAP;
}

// partition into 196 coarse buckets; packed edge: col | (row&511)<<17, val
__global__ __launch_bounds__(1024) void k_part(const int* __restrict__ rows,
                                               const int* __restrict__ cols,
                                               const float* __restrict__ vals,
                                               int* __restrict__ bcur,
                                               int2* __restrict__ tmp) {
  __shared__ int h[NB_BKT];   // hist, then global write cursor per bucket
  int t = threadIdx.x;
  for (int i = t; i < NB_BKT; i += 1024) h[i] = 0;
  __syncthreads();
  int base = blockIdx.x * PTILE;
  for (int i = t; i < PTILE; i += 1024) {
    int e = base + i;
    if (e < NNZ_E) atomicAdd(&h[rows[e] >> 9], 1);
  }
  __syncthreads();
  for (int i = t; i < NB_BKT; i += 1024) {
    int c = h[i];
    h[i] = c ? atomicAdd(&bcur[i], c) : 0;
  }
  __syncthreads();
  for (int i = t; i < PTILE; i += 1024) {
    int e = base + i;
    if (e < NNZ_E) {
      int rr = rows[e];
      int p = atomicAdd(&h[rr >> 9], 1);
      int2 o;
      o.x = cols[e] | ((rr & 511) << 17);
      o.y = __float_as_int(vals[e]);
      tmp[p] = o;
    }
  }
}

// final cursors -> bucket base positions (exclusive scan of counts)
__global__ void k_base(const int* __restrict__ bcur, int* __restrict__ bbase) {
  __shared__ int ts[256];
  int t = threadIdx.x;
  int v = (t < NB_BKT) ? (bcur[t] - t * BCAP) : 0;
  ts[t] = v;
  __syncthreads();
  for (int off = 1; off < 256; off <<= 1) {
    int x = ts[t];
    int a = (t >= off) ? ts[t - off] : 0;
    __syncthreads();
    ts[t] = x + a;
    __syncthreads();
  }
  if (t < NB_BKT) bbase[t] = (t == 0) ? 0 : ts[t - 1];
}

// one block per bucket: 512-row LDS counting sort -> final edges[] + rowptr
__global__ __launch_bounds__(1024) void k_sort(const int* __restrict__ bbase,
                                               const int* __restrict__ bcur,
                                               const int2* __restrict__ tmp,
                                               int2* __restrict__ edges,
                                               int* __restrict__ rowptr) {
  __shared__ int cnt[512];
  __shared__ int ts[512];
  int b = blockIdx.x, t = threadIdx.x;
  int src = b * BCAP;
  int n = bcur[b] - src;              // edges in this bucket
  int s = bbase[b];                   // global output base
  if (t < 512) cnt[t] = 0;
  __syncthreads();
  for (int i = t; i < n; i += 1024)
    atomicAdd(&cnt[(tmp[src + i].x >> 17) & 511], 1);
  __syncthreads();
  if (t < 512) ts[t] = cnt[t];
  __syncthreads();
  for (int off = 1; off < 512; off <<= 1) {
    int x = (t < 512) ? ts[t] : 0;
    int a = (t >= off && t < 512) ? ts[t - off] : 0;
    __syncthreads();
    if (t < 512) ts[t] = x + a;
    __syncthreads();
  }
  if (t < 512) {
    int pre = (t == 0) ? 0 : ts[t - 1];
    int grow = b * 512 + t;
    if (grow < N_NODES) rowptr[grow] = s + pre;
    cnt[t] = s + pre;                 // becomes per-row write cursor
  }
  __syncthreads();
  for (int i = t; i < n; i += 1024) {
    int2 p = tmp[src + i];
    int rl = (p.x >> 17) & 511;
    int pos = atomicAdd(&cnt[rl], 1);
    int2 o;
    o.x = p.x & 0x1FFFF;
    o.y = p.y;
    edges[pos] = o;
  }
  if (b == 0 && t == 0) rowptr[N_NODES] = NNZ_E;
}

// ---------------- fused prep: fp32->bf16 convert + weight packing ----------------
// blocks [0,12500): cvt; [12500,12884): prepW1; [12884,13140): prepW2

__global__ __launch_bounds__(256) void k_prep(
    const float4* __restrict__ x, const float* __restrict__ W1,
    const float* __restrict__ W2, ushort4* __restrict__ xb,
    ushort_t* __restrict__ W1p, ushort_t* __restrict__ W2p) {
  int b = blockIdx.x;
  if (b < 12500) {
    int i = b * 256 + threadIdx.x;
    float4 v = x[i];
    ushort4 o;
    o.x = f2bf(v.x); o.y = f2bf(v.y); o.z = f2bf(v.z); o.w = f2bf(v.w);
    xb[i] = o;
  } else if (b < 12884) {
    int kp = b - 12500;   // 0..383
    int n  = threadIdx.x; // 0..255
    int ch = kp >> 7;
    int f  = kp & 127;
    float v;
    if (ch == 0)      v = W1[(f*3+0)*256+n] - W1[(f*3+2)*256+n];
    else if (ch == 1) v = W1[(f*3+1)*256+n];
    else              v = 2.0f * W1[(f*3+2)*256+n];
    int kb = kp >> 5, kr = kp & 31;
    int lane = ((kr >> 3) << 4) | (n & 15);
    W1p[(((size_t)kb * 16 + (n >> 4)) * 64 + lane) * 8 + (kr & 7)] = f2bf(v);
  } else {
    int f = b - 12884;    // 0..255
    int c = threadIdx.x;
    if (c < 192) {
      int g = c >> 6, n = c & 63;
      float v;
      if (g == 0)      v = W2[(f*3+0)*64+n] - W2[(f*3+2)*64+n];
      else if (g == 1) v = W2[(f*3+1)*64+n];
      else             v = 2.0f * W2[(f*3+2)*64+n];
      int kb = f >> 5, kr = f & 31;
      int nb = c >> 4;
      int lane = ((kr >> 3) << 4) | (c & 15);
      W2p[(((size_t)kb * 12 + nb) * 64 + lane) * 8 + (kr & 7)] = f2bf(v);
    }
  }
}

// ---------------- SpMM, 128 features (layer 1) ----------------
// R1 form (best measured). Gather plateau ~3.5 TB/s confirmed across 4
// shapes. 3-way split kept: the top-5 view only shows the single most
// expensive kernel's iterations, so keeping chunks at ~36us preserves
// diagnostic visibility of whatever becomes the new max.

__global__ __launch_bounds__(256) void k_spmm128(
    const int* __restrict__ rowptr, const int2* __restrict__ edges,
    const ushort_t* __restrict__ in, ushort_t* __restrict__ out, int row0) {
  int r = __builtin_amdgcn_readfirstlane(row0 + blockIdx.x * 4 + (threadIdx.x >> 6));
  int f = threadIdx.x & 63;
  int e0 = rowptr[r], e1 = rowptr[r + 1];
  float a0 = 0.f, a1 = 0.f;
  int e = e0;
  for (; e + 16 <= e1; e += 16) {
    int2 E[16];
#pragma unroll
    for (int j = 0; j < 16; ++j) E[j] = edges[e + j];
    uint_t q[16];
#pragma unroll
    for (int j = 0; j < 16; ++j)
      q[j] = *(const uint_t*)(in + (size_t)E[j].x * 128 + 2 * f);
#pragma unroll
    for (int j = 0; j < 16; ++j) {
      float v = __int_as_float(E[j].y);
      a0 = fmaf(v, bf2f(q[j] & 0xFFFFu), a0);
      a1 = fmaf(v, bf2f(q[j] >> 16), a1);
    }
  }
  for (; e + 4 <= e1; e += 4) {
    int2 E[4];
#pragma unroll
    for (int j = 0; j < 4; ++j) E[j] = edges[e + j];
    uint_t q[4];
#pragma unroll
    for (int j = 0; j < 4; ++j)
      q[j] = *(const uint_t*)(in + (size_t)E[j].x * 128 + 2 * f);
#pragma unroll
    for (int j = 0; j < 4; ++j) {
      float v = __int_as_float(E[j].y);
      a0 = fmaf(v, bf2f(q[j] & 0xFFFFu), a0);
      a1 = fmaf(v, bf2f(q[j] >> 16), a1);
    }
  }
  for (; e < e1; ++e) {
    int2 E = edges[e];
    uint_t q = *(const uint_t*)(in + (size_t)E.x * 128 + 2 * f);
    float v = __int_as_float(E.y);
    a0 = fmaf(v, bf2f(q & 0xFFFFu), a0);
    a1 = fmaf(v, bf2f(q >> 16), a1);
  }
  uint_t o = ((uint_t)f2bf(a1) << 16) | (uint_t)f2bf(a0);
  *(uint_t*)(out + (size_t)r * 128 + 2 * f) = o;
}

// ---------------- SpMM, 64 features: u = p1 + L p2 ----------------

__global__ __launch_bounds__(256) void k_spmm64_add(
    const int* __restrict__ rowptr, const int2* __restrict__ edges,
    const ushort_t* __restrict__ p2, const ushort_t* __restrict__ p1,
    ushort_t* __restrict__ u) {
  int r = __builtin_amdgcn_readfirstlane(blockIdx.x * 4 + (threadIdx.x >> 6));
  int lane = threadIdx.x & 63;
  int half = lane >> 5, l5 = lane & 31;
  int e0 = rowptr[r], e1 = rowptr[r + 1];
  float a0 = 0.f, a1 = 0.f;
  int e = e0;
  for (; e + 16 <= e1; e += 16) {      // 8 pairs
    int2 Ea[8], Eb[8];
#pragma unroll
    for (int j = 0; j < 8; ++j) { Ea[j] = edges[e + 2*j]; Eb[j] = edges[e + 2*j + 1]; }
    uint_t q[8];
#pragma unroll
    for (int j = 0; j < 8; ++j) {
      int c = half ? Eb[j].x : Ea[j].x;
      q[j] = *(const uint_t*)(p2 + (size_t)c * 64 + 2 * l5);
    }
#pragma unroll
    for (int j = 0; j < 8; ++j) {
      float v = __int_as_float(half ? Eb[j].y : Ea[j].y);
      a0 = fmaf(v, bf2f(q[j] & 0xFFFFu), a0);
      a1 = fmaf(v, bf2f(q[j] >> 16), a1);
    }
  }
  for (; e + 2 <= e1; e += 2) {        // 1 pair
    int2 Ea = edges[e], Eb = edges[e + 1];
    int c = half ? Eb.x : Ea.x;
    uint_t q = *(const uint_t*)(p2 + (size_t)c * 64 + 2 * l5);
    float v = __int_as_float(half ? Eb.y : Ea.y);
    a0 = fmaf(v, bf2f(q & 0xFFFFu), a0);
    a1 = fmaf(v, bf2f(q >> 16), a1);
  }
  if (e < e1) {                        // odd leftover: high half contributes 0
    int2 Ea = edges[e];
    uint_t q = *(const uint_t*)(p2 + (size_t)Ea.x * 64 + 2 * l5);
    float v = half ? 0.f : __int_as_float(Ea.y);
    a0 = fmaf(v, bf2f(q & 0xFFFFu), a0);
    a1 = fmaf(v, bf2f(q >> 16), a1);
  }
  a0 += __shfl_xor(a0, 32);
  a1 += __shfl_xor(a1, 32);
  if (half == 0) {
    uint_t pp = *(const uint_t*)(p1 + (size_t)r * 64 + 2 * l5);
    float b0 = a0 + bf2f(pp & 0xFFFFu);
    float b1 = a1 + bf2f(pp >> 16);
    *(uint_t*)(u + (size_t)r * 64 + 2 * l5) = pk(b0, b1);
  }
}

// ---------------- SpMM, 64 features over idx rows: out = p0[idx] + L u ----------------

__global__ __launch_bounds__(256) void k_spmm64_idx(
    const int* __restrict__ rowptr, const int2* __restrict__ edges,
    const ushort_t* __restrict__ u, const float* __restrict__ p0,
    const int* __restrict__ idx, float* __restrict__ out) {
  int o = __builtin_amdgcn_readfirstlane(blockIdx.x * 4 + (threadIdx.x >> 6));
  int lane = threadIdx.x & 63;
  int half = lane >> 5, l5 = lane & 31;
  int r = __builtin_amdgcn_readfirstlane(idx[o]);
  int e0 = rowptr[r], e1 = rowptr[r + 1];
  float a0 = 0.f, a1 = 0.f;
  int e = e0;
  for (; e + 16 <= e1; e += 16) {      // 8 pairs
    int2 Ea[8], Eb[8];
#pragma unroll
    for (int j = 0; j < 8; ++j) { Ea[j] = edges[e + 2*j]; Eb[j] = edges[e + 2*j + 1]; }
    uint_t q[8];
#pragma unroll
    for (int j = 0; j < 8; ++j) {
      int c = half ? Eb[j].x : Ea[j].x;
      q[j] = *(const uint_t*)(u + (size_t)c * 64 + 2 * l5);
    }
#pragma unroll
    for (int j = 0; j < 8; ++j) {
      float v = __int_as_float(half ? Eb[j].y : Ea[j].y);
      a0 = fmaf(v, bf2f(q[j] & 0xFFFFu), a0);
      a1 = fmaf(v, bf2f(q[j] >> 16), a1);
    }
  }
  for (; e + 2 <= e1; e += 2) {
    int2 Ea = edges[e], Eb = edges[e + 1];
    int c = half ? Eb.x : Ea.x;
    uint_t q = *(const uint_t*)(u + (size_t)c * 64 + 2 * l5);
    float v = __int_as_float(half ? Eb.y : Ea.y);
    a0 = fmaf(v, bf2f(q & 0xFFFFu), a0);
    a1 = fmaf(v, bf2f(q >> 16), a1);
  }
  if (e < e1) {
    int2 Ea = edges[e];
    uint_t q = *(const uint_t*)(u + (size_t)Ea.x * 64 + 2 * l5);
    float v = half ? 0.f : __int_as_float(Ea.y);
    a0 = fmaf(v, bf2f(q & 0xFFFFu), a0);
    a1 = fmaf(v, bf2f(q >> 16), a1);
  }
  a0 += __shfl_xor(a0, 32);
  a1 += __shfl_xor(a1, 32);
  if (half == 0) {
    float2 b = *(const float2*)(p0 + (size_t)r * 64 + 2 * l5);
    float2 ww; ww.x = b.x + a0; ww.y = b.y + a1;
    *(float2*)(out + (size_t)o * 64 + 2 * l5) = ww;
  }
}

// ---------------- GEMM1: h = relu([x|T1|U] @ Weff1 + b1), M=100k K=384 N=256 ----------
// LDS-staged 2-barrier structure (m97): 128x128 tile, BK=64, 6 K-steps.
// A staged with k-chunk XOR swizzle via pre-swizzled global source; B's
// fragment-pack is already contiguous 1KB chunks (conflict-free).

__global__ __launch_bounds__(256) void k_gemm1(
    const ushort_t* __restrict__ A0, const ushort_t* __restrict__ A1,
    const ushort_t* __restrict__ A2, const ushort_t* __restrict__ Bp,
    const float* __restrict__ bias, ushort_t* __restrict__ h) {
  __shared__ ushort_t sA[128 * 64];   // 16 KB, [row][k8-slot], slot = k8 ^ (row&7)
  __shared__ ushort_t sB[16 * 512];   // 16 KB, 16 chunks of (kb_l, nb_l)
  int t = threadIdx.x, w = t >> 6, l = t & 63;
  int mt = blockIdx.x >> 1, ct = blockIdx.x & 1;
  int r0 = mt * 128;
  int wr = w >> 1, wc = w & 1;
  floatx4 acc[4][4] = {};
  for (int s = 0; s < 6; ++s) {
    const ushort_t* Asrc = (s < 2) ? A0 : (s < 4) ? A1 : A2;
    int kloc = (s & 1) << 6;
#pragma unroll
    for (int c = 0; c < 4; ++c) {     // A: 128 rows x 64 k = 16KB, 4 calls
      int rl = c * 32 + (t >> 3);
      int row = r0 + rl; if (row > N_NODES - 1) row = N_NODES - 1;
      int k8f = (t & 7) ^ (rl & 7);   // pre-swizzled global source
      __builtin_amdgcn_global_load_lds(
          (const void*)(Asrc + (size_t)row * 128 + kloc + k8f * 8),
          (void*)(sA + (c * 4 + w) * 512), 16, 0, 0);
    }
#pragma unroll
    for (int i = 0; i < 4; ++i) {     // B: 16 chunks x 1KB, 4 calls
      int lc = i * 4 + w;
      int chunkid = (s * 2 + (lc >> 3)) * 16 + ct * 8 + (lc & 7);
      __builtin_amdgcn_global_load_lds(
          (const void*)(Bp + (size_t)chunkid * 512 + l * 8),
          (void*)(sB + lc * 512), 16, 0, 0);
    }
    __syncthreads();
#pragma unroll
    for (int kb = 0; kb < 2; ++kb) {
      bf16x8 aF[4], bF[4];
      int k8 = kb * 4 + (l >> 4);
#pragma unroll
      for (int mi = 0; mi < 4; ++mi) {
        int rl = wr * 64 + mi * 16 + (l & 15);
        aF[mi] = *(const bf16x8*)(sA + rl * 64 + ((k8 ^ (rl & 7)) * 8));
      }
#pragma unroll
      for (int nt = 0; nt < 4; ++nt)
        bF[nt] = *(const bf16x8*)(sB + ((size_t)(kb * 8 + wc * 4 + nt) * 64 + l) * 8);
#pragma unroll
      for (int nt = 0; nt < 4; ++nt)
#pragma unroll
        for (int mi = 0; mi < 4; ++mi)
          acc[mi][nt] = __builtin_amdgcn_mfma_f32_16x16x32_bf16(aF[mi], bF[nt], acc[mi][nt], 0, 0, 0);
    }
    __syncthreads();
  }
  int col0 = ct * 128 + wc * 64 + (l & 15);
  int rb0 = r0 + wr * 64 + ((l >> 4) << 2);
#pragma unroll
  for (int nt = 0; nt < 4; ++nt) {
    int col = col0 + nt * 16;
    float bv = bias[col];
#pragma unroll
    for (int mi = 0; mi < 4; ++mi) {
#pragma unroll
      for (int rg = 0; rg < 4; ++rg) {
        int row = rb0 + mi * 16 + rg;
        if (row < N_NODES) {
          float v = acc[mi][nt][rg] + bv;
          v = v > 0.f ? v : 0.f;
          h[(size_t)row * 256 + col] = f2bf(v);
        }
      }
    }
  }
}

// ---------------- GEMM2: [p0|p1|p2] = h @ Weff2 (+b2 on p0), M=100k K=256 N=192 -------
// Same LDS-staged structure: 256x64 tile (block-uniform output slab ct),
// 4 K-steps. Grid = 391 Mtiles x 3 slabs = 1173.

__global__ __launch_bounds__(256) void k_gemm2(
    const ushort_t* __restrict__ A, const ushort_t* __restrict__ Bp,
    const float* __restrict__ bias, float* __restrict__ p0,
    ushort_t* __restrict__ p1, ushort_t* __restrict__ p2) {
  __shared__ ushort_t sA[256 * 64];   // 32 KB
  __shared__ ushort_t sB[8 * 512];    // 8 KB
  int t = threadIdx.x, w = t >> 6, l = t & 63;
  int mt = blockIdx.x / 3, ct = blockIdx.x - mt * 3;
  int r0 = mt * 256;
  floatx4 acc[4][4] = {};
  for (int s = 0; s < 4; ++s) {
    int kloc = s * 64;
#pragma unroll
    for (int c = 0; c < 8; ++c) {     // A: 256 rows x 64 k = 32KB, 8 calls
      int rl = c * 32 + (t >> 3);
      int row = r0 + rl; if (row > N_NODES - 1) row = N_NODES - 1;
      int k8f = (t & 7) ^ (rl & 7);
      __builtin_amdgcn_global_load_lds(
          (const void*)(A + (size_t)row * 256 + kloc + k8f * 8),
          (void*)(sA + (c * 4 + w) * 512), 16, 0, 0);
    }
#pragma unroll
    for (int i = 0; i < 2; ++i) {     // B: 8 chunks x 1KB, 2 calls
      int lc = i * 4 + w;
      int chunkid = (s * 2 + (lc >> 2)) * 12 + ct * 4 + (lc & 3);
      __builtin_amdgcn_global_load_lds(
          (const void*)(Bp + (size_t)chunkid * 512 + l * 8),
          (void*)(sB + lc * 512), 16, 0, 0);
    }
    __syncthreads();
#pragma unroll
    for (int kb = 0; kb < 2; ++kb) {
      bf16x8 aF[4], bF[4];
      int k8 = kb * 4 + (l >> 4);
#pragma unroll
      for (int mi = 0; mi < 4; ++mi) {
        int rl = w * 64 + mi * 16 + (l & 15);
        aF[mi] = *(const bf16x8*)(sA + rl * 64 + ((k8 ^ (rl & 7)) * 8));
      }
#pragma unroll
      for (int nt = 0; nt < 4; ++nt)
        bF[nt] = *(const bf16x8*)(sB + ((size_t)(kb * 4 + nt) * 64 + l) * 8);
#pragma unroll
      for (int nt = 0; nt < 4; ++nt)
#pragma unroll
        for (int mi = 0; mi < 4; ++mi)
          acc[mi][nt] = __builtin_amdgcn_mfma_f32_16x16x32_bf16(aF[mi], bF[nt], acc[mi][nt], 0, 0, 0);
    }
    __syncthreads();
  }
  int c16 = l & 15;
  int rb0 = r0 + w * 64 + ((l >> 4) << 2);
  if (ct == 0) {
#pragma unroll
    for (int nt = 0; nt < 4; ++nt) {
      float bv = bias[nt * 16 + c16];
#pragma unroll
      for (int mi = 0; mi < 4; ++mi)
#pragma unroll
        for (int rg = 0; rg < 4; ++rg) {
          int row = rb0 + mi * 16 + rg;
          if (row < N_NODES)
            p0[(size_t)row * 64 + nt * 16 + c16] = acc[mi][nt][rg] + bv;
        }
    }
  } else {
    ushort_t* dst = (ct == 1) ? p1 : p2;
#pragma unroll
    for (int nt = 0; nt < 4; ++nt)
#pragma unroll
      for (int mi = 0; mi < 4; ++mi)
#pragma unroll
        for (int rg = 0; rg < 4; ++rg) {
          int row = rb0 + mi * 16 + rg;
          if (row < N_NODES)
            dst[(size_t)row * 64 + nt * 16 + c16] = f2bf(acc[mi][nt][rg]);
        }
  }
}

// ---------------- launch ----------------

extern "C" void kernel_launch(void* const* d_in, const int* in_sizes, int n_in,
                              void* d_out, int out_size, void* d_ws, size_t ws_size,
                              hipStream_t stream) {
  const float* x    = (const float*)d_in[0];
  const float* vals = (const float*)d_in[1];
  const float* W1   = (const float*)d_in[2];
  const float* b1   = (const float*)d_in[3];
  const float* W2   = (const float*)d_in[4];
  const float* b2   = (const float*)d_in[5];
  const int*   rows = (const int*)d_in[6];
  const int*   cols = (const int*)d_in[7];
  const int*   idx  = (const int*)d_in[8];
  float* out = (float*)d_out;

  char* w = (char*)d_ws;
  size_t off = 0;
  auto take = [&](size_t b) -> char* {
    char* p = w + off;
    off += (b + 255) & ~(size_t)255;
    return p;
  };
  int*      bbase   = (int*)take((size_t)NB_BKT * 4);
  int*      bcur    = (int*)take((size_t)NB_BKT * 4);
  int*      rowptr  = (int*)take((size_t)(N_NODES + 1) * 4);
  int2*     tmp     = (int2*)take((size_t)NB_BKT * BCAP * 8);
  int2*     edges   = (int2*)take((size_t)NNZ_E * 8);
  ushort_t* xb      = (ushort_t*)take((size_t)N_NODES * 128 * 2);  // later: p0 (fp32 100k x 64)
  ushort_t* T1a     = (ushort_t*)take((size_t)N_NODES * 128 * 2);  // later: p1 | p2
  ushort_t* U1      = (ushort_t*)take((size_t)N_NODES * 128 * 2);  // later: u
  ushort_t* h       = (ushort_t*)take((size_t)N_NODES * 256 * 2);
  ushort_t* W1p     = (ushort_t*)take((size_t)384 * 256 * 2);
  ushort_t* W2p     = (ushort_t*)take((size_t)256 * 192 * 2);

  // overlays (dead after GEMM1 consumes xb/T1a/U1)
  float*    p0 = (float*)xb;                                   // 25.6 MB, exact fit
  ushort_t* p1 = T1a;                                          // 12.8 MB
  ushort_t* p2 = T1a + (size_t)N_NODES * 64;                   // 12.8 MB
  ushort_t* u  = U1;                                           // 12.8 MB

  // CSR build (graph shared by both layers)
  k_init<<<1, 256, 0, stream>>>(bcur);
  k_part<<<PBLOCKS, 1024, 0, stream>>>(rows, cols, vals, bcur, tmp);
  k_base<<<1, 256, 0, stream>>>(bcur, bbase);
  k_sort<<<NB_BKT, 1024, 0, stream>>>(bbase, bcur, tmp, edges, rowptr);

  // prep (cvt + both weight packs fused)
  k_prep<<<13140, 256, 0, stream>>>((const float4*)x, W1, W2, (ushort4*)xb, W1p, W2p);

  // layer 1: T1 = L x ; U = L T1 ; h = relu([x|T1|U] @ Weff1 + b1)
  k_spmm128<<<8334, 256, 0, stream>>>(rowptr, edges, xb, T1a, 0);
  k_spmm128<<<8334, 256, 0, stream>>>(rowptr, edges, xb, T1a, 33336);
  k_spmm128<<<8332, 256, 0, stream>>>(rowptr, edges, xb, T1a, 66672);
  k_spmm128<<<8334, 256, 0, stream>>>(rowptr, edges, T1a, U1, 0);
  k_spmm128<<<8334, 256, 0, stream>>>(rowptr, edges, T1a, U1, 33336);
  k_spmm128<<<8332, 256, 0, stream>>>(rowptr, edges, T1a, U1, 66672);
  k_gemm1<<<1564, 256, 0, stream>>>(xb, T1a, U1, W1p, b1, h);

  // layer 2 (L pushed past the GEMM): [p0|p1|p2] = h @ Weff2 ; u = p1 + L p2 ;
  // out = p0[idx] + (L u)[idx]
  k_gemm2<<<1173, 256, 0, stream>>>(h, W2p, b2, p0, p1, p2);
  k_spmm64_add<<<N_NODES / 4, 256, 0, stream>>>(rowptr, edges, p2, p1, u);
  k_spmm64_idx<<<N_IDX / 4, 256, 0, stream>>>(rowptr, edges, u, p0, idx, out);
}